// Round 9
// baseline (1222.998 us; speedup 1.0000x reference)
//
#include <hip/hip_runtime.h>
#include <cstdint>
#include <cstddef>

// ---------------------------------------------------------------------------
// MPML_57509612093615 : conv stack + BN + attention/GCN graph + 2-layer LSTM
// Round 13: pre-converted bf16 whh for the recurrent loop. R12 counters:
// XCD swizzle cut input-gemm FETCH 293->55MB (theory confirmed) but dur flat
// -> staging conversion VALU, not HBM, binds these GEMMs. The recurrent loop
// re-converts the SAME whh tile f32->bf16 hi/lo every step (20 dispatches,
// ~10 VALU/elem on 2/3 of staged data). Fix: conv_bf16_k converts whh once
// per layer (identical f2bf formulas -> bit-identical staged values) into
// the pin region (dead during each recurrent loop); gemm_rec_k stages B via
// plain short8 copies. Input GEMMs/graph/convs byte-identical to R12.
// Shapes: B=64 T=10 SEG=1184 SIG=8 ADJ=64 HID=1024 NCLS=5, N=B*T=640
// ---------------------------------------------------------------------------

#define TOPK_K 1638

typedef short short8 __attribute__((ext_vector_type(8)));
typedef float fl4 __attribute__((ext_vector_type(4)));

// pad-every-8 LDS index: stride between 8-element groups becomes 9 banks
#define XI(l) ((l) + ((l) >> 3))

// ---------------- generic conv1d (rolling register window) ----------------
template<int CI, int CO, int K, int LIN, int LOUT, int NLG, bool XPOSED>
__global__ __launch_bounds__(256) void conv1d_k(const float* __restrict__ xin,
                                                const float* __restrict__ wg,
                                                const float* __restrict__ bg,
                                                float* __restrict__ y)
{
  constexpr int LT = 8;
  constexpr int CHUNK = NLG * LT;
  constexpr int NCHUNK = (LOUT + CHUNK - 1) / CHUNK;
  constexpr int TW = CHUNK + K - 1;
  constexpr int TWP = TW + (TW >> 3) + 2;
  __shared__ float xs[CI][TWP];
  __shared__ float ws[CI * K * CO];   // [ci][k][co]
  const int bx = blockIdx.x;
  const int n = bx / NCHUNK;
  const int l0 = (bx % NCHUNK) * CHUNK;
  const int tid = threadIdx.x;

  for (int i = tid; i < CI * K * CO; i += 256) {
    int co = i % CO, rest = i / CO;          // rest = ci*K + k
    ws[i] = wg[co * (CI * K) + rest];
  }
  if (XPOSED && CI == 8) {
    // conv1: one thread per position l, coalesced float4 x2 loads
    for (int dl = tid; dl < TW; dl += 256) {
      int l = l0 + dl;
      if (l < LIN) {
        const float* xp = xin + ((size_t)n * LIN + l) * 8;
        float4 v0 = *(const float4*)xp;
        float4 v1 = *(const float4*)(xp + 4);
        xs[0][XI(dl)] = v0.x; xs[1][XI(dl)] = v0.y;
        xs[2][XI(dl)] = v0.z; xs[3][XI(dl)] = v0.w;
        xs[4][XI(dl)] = v1.x; xs[5][XI(dl)] = v1.y;
        xs[6][XI(dl)] = v1.z; xs[7][XI(dl)] = v1.w;
      } else {
#pragma unroll
        for (int ci = 0; ci < 8; ci++) xs[ci][XI(dl)] = 0.f;
      }
    }
  } else {
    for (int i = tid; i < CI * TW; i += 256) {
      int ci = i / TW, dl = i % TW, l = l0 + dl;
      float v = 0.f;
      if (l < LIN) v = XPOSED ? xin[((size_t)n * LIN + l) * CI + ci]
                              : xin[((size_t)n * CI + ci) * LIN + l];
      xs[ci][XI(dl)] = v;
    }
  }
  __syncthreads();

  const int lg = tid % NLG, co = tid / NLG;  // NLG*CO == 256
  float acc[LT];
  const float bco = bg[co];
#pragma unroll
  for (int j = 0; j < LT; j++) acc[j] = bco;

  for (int ci = 0; ci < CI; ci++) {
    float win[LT];
#pragma unroll
    for (int j = 0; j < LT; j++) win[j] = xs[ci][XI(lg * LT + j)];
#pragma unroll
    for (int k = 0; k < K; k++) {
      const float wv = ws[(ci * K + k) * CO + co];
#pragma unroll
      for (int j = 0; j < LT; j++) acc[j] = fmaf(win[j], wv, acc[j]);
      if (k < K - 1) {
#pragma unroll
        for (int j = 0; j < LT - 1; j++) win[j] = win[j + 1];
        win[LT - 1] = xs[ci][XI(lg * LT + LT + k)];
      }
    }
  }
  float* yp = y + ((size_t)n * CO + co) * LOUT;
  const int lb = l0 + lg * LT;
#pragma unroll
  for (int j = 0; j < LT; j++)
    if (lb + j < LOUT) yp[lb + j] = acc[j];
}

// ---------------- BN stats (f64 accumulation, atomic) ----------------
__global__ __launch_bounds__(256) void bn_stats_k(const float* __restrict__ y,
                                                  int C, int L,
                                                  double* __restrict__ st)
{
  const int c = blockIdx.x, slab = blockIdx.y, tid = threadIdx.x;
  double s = 0.0, q = 0.0;
  const int n0 = slab * 64;
  for (int n = n0; n < n0 + 64; n++) {
    const float* p = y + ((size_t)n * C + c) * L;
    for (int l = tid; l < L; l += 256) { float v = p[l]; s += v; q += (double)v * v; }
  }
  __shared__ double rs[256], rq[256];
  rs[tid] = s; rq[tid] = q; __syncthreads();
  for (int off = 128; off; off >>= 1) {
    if (tid < off) { rs[tid] += rs[tid + off]; rq[tid] += rq[tid + off]; }
    __syncthreads();
  }
  if (tid == 0) { atomicAdd(&st[c], rs[0]); atomicAdd(&st[C + c], rq[0]); }
}

__global__ void bn_fin_k(const double* __restrict__ st, const float* __restrict__ g,
                         const float* __restrict__ b, int C, double invcnt,
                         float* __restrict__ scsh)
{
  int c = threadIdx.x;
  if (c < C) {
    double m = st[c] * invcnt;
    double v = st[C + c] * invcnt - m * m;
    float sc = g[c] * (float)(1.0 / sqrt(v + 1e-5));
    scsh[c] = sc;
    scsh[C + c] = b[c] - (float)m * sc;
  }
}

// ---------------- BN apply + relu + maxpool ----------------
template<int WIN, int STRIDE>
__global__ __launch_bounds__(256) void bn_pool_k(const float* __restrict__ y,
                                                 const float* __restrict__ scsh,
                                                 int C, int LI, int LO, int total,
                                                 float* __restrict__ o)
{
  int idx = blockIdx.x * 256 + threadIdx.x;
  if (idx >= total) return;
  int j = idx % LO; int r = idx / LO; int c = r % C; int n = r / C;
  float sc = scsh[c], sh = scsh[C + c];
  const float* p = y + ((size_t)n * C + c) * LI + j * STRIDE;
  float m = 0.f;   // relu outputs are >= 0
#pragma unroll
  for (int k = 0; k < WIN; k++) {
    float v = fmaxf(fmaf(p[k], sc, sh), 0.f);
    m = fmaxf(m, v);
  }
  o[idx] = m;
}

// ---------------- graph-stage 64x64 matmuls, fl4 LDS both operands --------

// C = A @ B : acc[r][c] += sum_d Aa[i0+r][d] * Bb[d][j0+c]   (d-order exact)
__device__ __forceinline__ void mm_AB_l(float acc[4][4], const float (*Aa)[68],
                                        const float (*Bb)[68], int i0, int j0)
{
#pragma unroll
  for (int r = 0; r < 4; r++)
#pragma unroll
    for (int c = 0; c < 4; c++) acc[r][c] = 0.f;
#pragma unroll 4
  for (int d = 0; d < 64; d += 4) {
    fl4 a4[4];
#pragma unroll
    for (int r = 0; r < 4; r++) a4[r] = *(const fl4*)&Aa[i0 + r][d];
#pragma unroll
    for (int k = 0; k < 4; k++) {
      fl4 b4 = *(const fl4*)&Bb[d + k][j0];
#pragma unroll
      for (int r = 0; r < 4; r++)
#pragma unroll
        for (int c = 0; c < 4; c++) acc[r][c] = fmaf(a4[r][k], b4[c], acc[r][c]);
    }
  }
}

// C = A^T @ B : acc[r][c] += sum_d Aa[d][i0+r] * Bb[d][j0+c]
__device__ __forceinline__ void mm_AtB_l(float acc[4][4], const float (*Aa)[68],
                                         const float (*Bb)[68], int i0, int j0)
{
#pragma unroll
  for (int r = 0; r < 4; r++)
#pragma unroll
    for (int c = 0; c < 4; c++) acc[r][c] = 0.f;
#pragma unroll 4
  for (int d = 0; d < 64; d++) {
    fl4 a4 = *(const fl4*)&Aa[d][i0];
    fl4 b4 = *(const fl4*)&Bb[d][j0];
#pragma unroll
    for (int r = 0; r < 4; r++)
#pragma unroll
      for (int c = 0; c < 4; c++) acc[r][c] = fmaf(a4[r], b4[c], acc[r][c]);
  }
}

// direct stage: W[row][col] = src[row*64+col] (vectorized, conflict-clean)
__device__ __forceinline__ void stage_w_direct(float (*W)[68],
                                               const float* __restrict__ src, int tid)
{
  for (int fi = tid; fi < 1024; fi += 256) {
    int row = fi >> 4, cq = fi & 15;
    *(fl4*)&W[row][cq * 4] = *(const fl4*)&src[row * 64 + cq * 4];
  }
}

// transpose stage: W[d][j] = src[j*64+d] (coalesced reads, scalar writes)
__device__ __forceinline__ void stage_w_xpose(float (*W)[68],
                                              const float* __restrict__ src, int tid)
{
  for (int e = tid; e < 4096; e += 256)
    W[e & 63][e >> 6] = src[e];
}

// 256-thread row softmax: 4 threads per row (consecutive lanes), shfl_xor combine
__device__ __forceinline__ void softmax_rows256(float (*M)[68], int tid)
{
  const int row = tid >> 2, q = tid & 3, c0 = q * 16;
  float mx = -3.4e38f;
#pragma unroll
  for (int j = 0; j < 16; j++) mx = fmaxf(mx, M[row][c0 + j]);
  mx = fmaxf(mx, __shfl_xor(mx, 1));
  mx = fmaxf(mx, __shfl_xor(mx, 2));
  float s = 0.f;
#pragma unroll
  for (int j = 0; j < 16; j++) {
    float e = expf(M[row][c0 + j] - mx);
    M[row][c0 + j] = e; s += e;
  }
  s += __shfl_xor(s, 1);
  s += __shfl_xor(s, 2);
  float inv = 1.f / s;
#pragma unroll
  for (int j = 0; j < 16; j++) M[row][c0 + j] *= inv;
}

__device__ __forceinline__ unsigned f2key(float f)
{
  unsigned b = __float_as_uint(f);
  return (b & 0x80000000u) ? ~b : (b | 0x80000000u);
}

// one block per n: QKV attention + gaussian adj + gumbel topk + deg + GCNx2
__global__ __launch_bounds__(256) void graph_fused_k(
    const float* __restrict__ f1g, const float* __restrict__ u,
    const float* __restrict__ qw, const float* __restrict__ qb,
    const float* __restrict__ kw, const float* __restrict__ kb,
    const float* __restrict__ vw, const float* __restrict__ vb,
    const float* __restrict__ g1w, const float* __restrict__ g1b,
    const float* __restrict__ g2w, const float* __restrict__ g2b,
    float* __restrict__ seq)
{
  __shared__ __align__(16) float A[64][68], P[64][68], R[64][68], W[64][68];
  __shared__ float r2s[64], c2s[64], dv[64];
  __shared__ int cnt32[32];
  const int n = blockIdx.x, tid = threadIdx.x;
  const int tr = tid >> 4, tc = tid & 15, i0 = tr * 4, j0 = tc * 4;
  float acc[4][4];

  const float* fp = f1g + (size_t)n * 4096;
  stage_w_direct(A, fp, tid);                       // A = f1 (vectorized copy)
  stage_w_xpose(W, qw, tid);                        // W[d][j] = qw[j][d]
  __syncthreads();
  mm_AB_l(acc, A, W, i0, j0);                       // Q = f1 @ qw^T
#pragma unroll
  for (int r = 0; r < 4; r++)
#pragma unroll
    for (int c = 0; c < 4; c++) P[i0 + r][j0 + c] = acc[r][c] + qb[j0 + c];
  __syncthreads();
  stage_w_xpose(W, kw, tid);
  __syncthreads();
  mm_AB_l(acc, A, W, i0, j0);                       // K = f1 @ kw^T
#pragma unroll
  for (int r = 0; r < 4; r++)
#pragma unroll
    for (int c = 0; c < 4; c++) R[i0 + r][j0 + c] = acc[r][c] + kb[j0 + c];
  __syncthreads();
  mm_AtB_l(acc, R, P, i0, j0);                      // att_pre[w][v] = sum_h K[h][w]Q[h][v]
  __syncthreads();
#pragma unroll
  for (int r = 0; r < 4; r++)
#pragma unroll
    for (int c = 0; c < 4; c++) P[i0 + r][j0 + c] = 0.125f * acc[r][c];
  __syncthreads();
  softmax_rows256(P, tid);                          // P = att
  __syncthreads();
  stage_w_xpose(W, vw, tid);
  __syncthreads();
  mm_AB_l(acc, A, W, i0, j0);                       // V = f1 @ vw^T
#pragma unroll
  for (int r = 0; r < 4; r++)
#pragma unroll
    for (int c = 0; c < 4; c++) R[i0 + r][j0 + c] = acc[r][c] + vb[j0 + c];  // R = V
  __syncthreads();
  mm_AB_l(acc, R, P, i0, j0);                       // adj_att = V @ att
  __syncthreads();
#pragma unroll
  for (int r = 0; r < 4; r++)
#pragma unroll
    for (int c = 0; c < 4; c++) R[i0 + r][j0 + c] = acc[r][c];
  __syncthreads();
  softmax_rows256(R, tid);                          // R = S1
  __syncthreads();
  mm_AB_l(acc, A, A, i0, j0);                       // cross = f1 @ f1
  if (tid < 64) {
    float s = 0.f;
#pragma unroll
    for (int k = 0; k < 16; k++) {
      fl4 v = *(const fl4*)&A[tid][k * 4];
      s = fmaf(v[0], v[0], s); s = fmaf(v[1], v[1], s);
      s = fmaf(v[2], v[2], s); s = fmaf(v[3], v[3], s);
    }
    r2s[tid] = s;
  } else if (tid < 128) {
    int j = tid - 64; float s = 0.f;
    for (int d = 0; d < 64; d++) { float v = A[d][j]; s = fmaf(v, v, s); }
    c2s[j] = s;
  }
  __syncthreads();
#pragma unroll
  for (int r = 0; r < 4; r++)
#pragma unroll
    for (int c = 0; c < 4; c++) P[i0 + r][j0 + c] = acc[r][c];  // P = cross
  __syncthreads();
  for (int e = tid; e < 4096; e += 256) {
    int i = e >> 6, j = e & 63;
    P[i][j] = expf(-0.5f * (r2s[i] + c2s[j] - 2.f * P[i][j])); // adj_g, SIGMA=1
  }
  __syncthreads();
  softmax_rows256(P, tid);                          // P = S2
  __syncthreads();
  const float* un = u + (size_t)n * 4096;
  for (int e = tid; e < 4096; e += 256) {
    int i = e >> 6, j = e & 63;
    float uu = un[e];
    float gmb = -logf(-logf(uu + 1e-20f) + 1e-20f);
    R[i][j] = R[i][j] + P[i][j] + gmb;              // R = adj + gumbel
  }
  for (int i = tid; i < 32; i += 256) cnt32[i] = 0;
  __syncthreads();

  // exact radix select: TOPK_K-th largest of the 4096 values in R
  unsigned key[16];
#pragma unroll
  for (int e8 = 0; e8 < 16; e8++) {
    int e = tid * 16 + e8;
    key[e8] = f2key(R[e >> 6][e & 63]);
  }
  int kk = TOPK_K; unsigned high = 0u;
  for (int bit = 31; bit >= 0; bit--) {
    unsigned pref = (high >> bit) | 1u;
    int c_ = 0;
#pragma unroll
    for (int e8 = 0; e8 < 16; e8++) c_ += (int)((key[e8] >> bit) == pref);
    for (int off = 32; off; off >>= 1) c_ += __shfl_down(c_, off);
    if ((tid & 63) == 0) atomicAdd(&cnt32[bit], c_);
    __syncthreads();
    int tot = cnt32[bit];
    if (tot >= kk) high |= (1u << bit); else kk -= tot;
  }
  // deg over columns; diagonal forced to 1
  if (tid < 64) {
    int j = tid, dg = 1;
    for (int i = 0; i < 64; i++)
      if (i != j) dg += (int)(f2key(R[i][j]) >= high);
    dv[j] = 1.f / sqrtf((float)dg);
  }
  __syncthreads();
  for (int e = tid; e < 4096; e += 256) { int i = e >> 6; A[i][e & 63] *= dv[i]; }
  stage_w_direct(W, g1w, tid);                      // g1w already [d][j]
  __syncthreads();
  mm_AB_l(acc, A, W, i0, j0);                       // f2 pre-activation
  __syncthreads();
#pragma unroll
  for (int r = 0; r < 4; r++)
#pragma unroll
    for (int c = 0; c < 4; c++)
      P[i0 + r][j0 + c] = fmaxf(acc[r][c] + g1b[j0 + c], 0.f) * dv[i0 + r]; // dinv*f2
  stage_w_direct(W, g2w, tid);
  __syncthreads();
  mm_AB_l(acc, P, W, i0, j0);                       // f3 pre-activation
  float* sp = seq + (size_t)n * 4096;
#pragma unroll
  for (int r = 0; r < 4; r++)
#pragma unroll
    for (int c = 0; c < 4; c++)
      sp[(i0 + r) * 64 + j0 + c] = fmaxf(acc[r][c] + g2b[j0 + c], 0.f);
}

// ---------------- bf16 split helpers ----------------
__device__ __forceinline__ ushort f2bf_hi(float x)
{
  union { float f; unsigned u; } v; v.f = x;
  unsigned r = v.u + 0x7FFFu + ((v.u >> 16) & 1u);   // RNE to bf16
  return (ushort)(r >> 16);
}
__device__ __forceinline__ float bf2f(ushort h)
{
  union { unsigned u; float f; } v; v.u = ((unsigned)h) << 16;
  return v.f;
}

// ---------------- one-time fp32 -> bf16 hi/lo pre-conversion ----------------
// Same f2bf formulas as in-kernel staging -> bit-identical staged values.
__global__ __launch_bounds__(256) void conv_bf16_k(const float* __restrict__ src,
                                                   ushort* __restrict__ hi,
                                                   ushort* __restrict__ lo, int n4)
{
  int idx = blockIdx.x * 256 + threadIdx.x;
  if (idx >= n4) return;
  float4 v = *(const float4*)(src + (size_t)idx * 4);
  ushort h0 = f2bf_hi(v.x), h1 = f2bf_hi(v.y), h2 = f2bf_hi(v.z), h3 = f2bf_hi(v.w);
  uint2 hp = { (unsigned)h0 | ((unsigned)h1 << 16),
               (unsigned)h2 | ((unsigned)h3 << 16) };
  *(uint2*)(hi + (size_t)idx * 4) = hp;
  ushort l0 = f2bf_hi(v.x - bf2f(h0)), l1 = f2bf_hi(v.y - bf2f(h1));
  ushort l2 = f2bf_hi(v.z - bf2f(h2)), l3 = f2bf_hi(v.w - bf2f(h3));
  uint2 lp = { (unsigned)l0 | ((unsigned)l1 << 16),
               (unsigned)l2 | ((unsigned)l3 << 16) };
  *(uint2*)(lo + (size_t)idx * 4) = lp;
}

// ---------------- split-K GEMM via bf16-split MFMA (fp32 inputs) ----------
// part[z][m][j] = sum_{k in slice z} A[m][k]*B[j][k]   (3-product bf16 split)
// 1D grid nwg = MBLK*32*S, block 256 (4 waves, each 32x64 of 64x128 tile).
// XCD-chunked swizzle: swz=(flat&7)*(nwg/8)+flat/8 (bijective, nwg%8==0).
__global__ __launch_bounds__(256) void gemm_mfma_k(const float* __restrict__ Am,
                                                   const float* __restrict__ Bm,
                                                   float* __restrict__ Pm,
                                                   int KD, int KS, int Mtot, int MBLK)
{
  __shared__ __align__(16) ushort Ah[64][40], Al[64][40];
  __shared__ __align__(16) ushort Bh[128][40], Bl[128][40];
  const int nwg = gridDim.x;
  const int flat = blockIdx.x;
  const int swz = (flat & 7) * (nwg >> 3) + (flat >> 3);
  const int mb = swz % MBLK;
  const int rr = swz / MBLK;
  const int jb = rr & 31, z = rr >> 5;
  const int m0 = mb * 64, j0 = jb * 128;
  const int kbeg = z * KS;
  const int tid = threadIdx.x;
  const int wave = tid >> 6, lane = tid & 63;
  const int wr = (wave >> 1) * 32, wc = (wave & 1) * 64;
  const int lrow = lane & 15, koff = (lane >> 4) * 8;
  fl4 acc[2][4] = {};

  for (int kc = 0; kc < KS; kc += 32) {
    const int k0 = kbeg + kc;
    // stage A tile 64x32 (fp32 -> bf16 hi/lo)
#pragma unroll
    for (int i = 0; i < 2; i++) {
      int fi = tid + i * 256, m = fi >> 3, kq = fi & 7;
      float4 v = *(const float4*)(Am + (size_t)(m0 + m) * KD + k0 + kq * 4);
      ushort h0 = f2bf_hi(v.x), h1 = f2bf_hi(v.y), h2 = f2bf_hi(v.z), h3 = f2bf_hi(v.w);
      uint2 hp = { (unsigned)h0 | ((unsigned)h1 << 16),
                   (unsigned)h2 | ((unsigned)h3 << 16) };
      *(uint2*)&Ah[m][kq * 4] = hp;
      ushort l0 = f2bf_hi(v.x - bf2f(h0)), l1 = f2bf_hi(v.y - bf2f(h1));
      ushort l2 = f2bf_hi(v.z - bf2f(h2)), l3 = f2bf_hi(v.w - bf2f(h3));
      uint2 lp = { (unsigned)l0 | ((unsigned)l1 << 16),
                   (unsigned)l2 | ((unsigned)l3 << 16) };
      *(uint2*)&Al[m][kq * 4] = lp;
    }
    // stage B tile 128x32
#pragma unroll
    for (int i = 0; i < 4; i++) {
      int fi = tid + i * 256, j = fi >> 3, kq = fi & 7;
      float4 v = *(const float4*)(Bm + (size_t)(j0 + j) * KD + k0 + kq * 4);
      ushort h0 = f2bf_hi(v.x), h1 = f2bf_hi(v.y), h2 = f2bf_hi(v.z), h3 = f2bf_hi(v.w);
      uint2 hp = { (unsigned)h0 | ((unsigned)h1 << 16),
                   (unsigned)h2 | ((unsigned)h3 << 16) };
      *(uint2*)&Bh[j][kq * 4] = hp;
      ushort l0 = f2bf_hi(v.x - bf2f(h0)), l1 = f2bf_hi(v.y - bf2f(h1));
      ushort l2 = f2bf_hi(v.z - bf2f(h2)), l3 = f2bf_hi(v.w - bf2f(h3));
      uint2 lp = { (unsigned)l0 | ((unsigned)l1 << 16),
                   (unsigned)l2 | ((unsigned)l3 << 16) };
      *(uint2*)&Bl[j][kq * 4] = lp;
    }
    __syncthreads();
    short8 ah[2], al[2], bh[4], bl[4];
#pragma unroll
    for (int mt = 0; mt < 2; mt++) {
      ah[mt] = *(const short8*)&Ah[wr + mt * 16 + lrow][koff];
      al[mt] = *(const short8*)&Al[wr + mt * 16 + lrow][koff];
    }
#pragma unroll
    for (int nt = 0; nt < 4; nt++) {
      bh[nt] = *(const short8*)&Bh[wc + nt * 16 + lrow][koff];
      bl[nt] = *(const short8*)&Bl[wc + nt * 16 + lrow][koff];
    }
#pragma unroll
    for (int mt = 0; mt < 2; mt++)
#pragma unroll
      for (int nt = 0; nt < 4; nt++) {
        acc[mt][nt] = __builtin_amdgcn_mfma_f32_16x16x32_bf16(ah[mt], bh[nt], acc[mt][nt], 0, 0, 0);
        acc[mt][nt] = __builtin_amdgcn_mfma_f32_16x16x32_bf16(ah[mt], bl[nt], acc[mt][nt], 0, 0, 0);
        acc[mt][nt] = __builtin_amdgcn_mfma_f32_16x16x32_bf16(al[mt], bh[nt], acc[mt][nt], 0, 0, 0);
      }
    __syncthreads();
  }
  float* op = Pm + ((size_t)z * Mtot + m0) * 4096 + j0;
#pragma unroll
  for (int mt = 0; mt < 2; mt++)
#pragma unroll
    for (int nt = 0; nt < 4; nt++) {
      int col = wc + nt * 16 + lrow;
#pragma unroll
      for (int r = 0; r < 4; r++) {
        int row = wr + mt * 16 + (lane >> 4) * 4 + r;
        op[(size_t)row * 4096 + col] = acc[mt][nt][r];
      }
    }
}

// ---------------- recurrent GEMM: pre-converted bf16 B, fp32 A ----------
// Same tile/fragment schedule as gemm_mfma_k; B staged by plain short8 copies
// from packed hi/lo buffers (no conversion VALU, half the staged ops).
// grid 256 = 32 jb x 8 z, MBLK=1 (m0=0), KS=128, KD=1024, Mtot=64.
__global__ __launch_bounds__(256) void gemm_rec_k(const float* __restrict__ Am,
                                                  const ushort* __restrict__ Bhg,
                                                  const ushort* __restrict__ Blg,
                                                  float* __restrict__ Pm,
                                                  int KD, int KS, int Mtot)
{
  __shared__ __align__(16) ushort Ah[64][40], Al[64][40];
  __shared__ __align__(16) ushort Bh[128][40], Bl[128][40];
  const int nwg = gridDim.x;
  const int flat = blockIdx.x;
  const int swz = (flat & 7) * (nwg >> 3) + (flat >> 3);
  const int jb = swz & 31, z = swz >> 5;
  const int j0 = jb * 128;
  const int kbeg = z * KS;
  const int tid = threadIdx.x;
  const int wave = tid >> 6, lane = tid & 63;
  const int wr = (wave >> 1) * 32, wc = (wave & 1) * 64;
  const int lrow = lane & 15, koff = (lane >> 4) * 8;
  fl4 acc[2][4] = {};

  for (int kc = 0; kc < KS; kc += 32) {
    const int k0 = kbeg + kc;
    // stage A tile 64x32 (fp32 -> bf16 hi/lo)
#pragma unroll
    for (int i = 0; i < 2; i++) {
      int fi = tid + i * 256, m = fi >> 3, kq = fi & 7;
      float4 v = *(const float4*)(Am + (size_t)m * KD + k0 + kq * 4);
      ushort h0 = f2bf_hi(v.x), h1 = f2bf_hi(v.y), h2 = f2bf_hi(v.z), h3 = f2bf_hi(v.w);
      uint2 hp = { (unsigned)h0 | ((unsigned)h1 << 16),
                   (unsigned)h2 | ((unsigned)h3 << 16) };
      *(uint2*)&Ah[m][kq * 4] = hp;
      ushort l0 = f2bf_hi(v.x - bf2f(h0)), l1 = f2bf_hi(v.y - bf2f(h1));
      ushort l2 = f2bf_hi(v.z - bf2f(h2)), l3 = f2bf_hi(v.w - bf2f(h3));
      uint2 lp = { (unsigned)l0 | ((unsigned)l1 << 16),
                   (unsigned)l2 | ((unsigned)l3 << 16) };
      *(uint2*)&Al[m][kq * 4] = lp;
    }
    // stage B tile 128x32: direct short8 copies from pre-converted buffers
#pragma unroll
    for (int i = 0; i < 2; i++) {
      int fi = tid + i * 256, j = fi >> 2, g8 = fi & 3;
      const size_t gsrc = (size_t)(j0 + j) * KD + k0 + g8 * 8;
      *(short8*)&Bh[j][g8 * 8] = *(const short8*)(Bhg + gsrc);
      *(short8*)&Bl[j][g8 * 8] = *(const short8*)(Blg + gsrc);
    }
    __syncthreads();
    short8 ah[2], al[2], bh[4], bl[4];
#pragma unroll
    for (int mt = 0; mt < 2; mt++) {
      ah[mt] = *(const short8*)&Ah[wr + mt * 16 + lrow][koff];
      al[mt] = *(const short8*)&Al[wr + mt * 16 + lrow][koff];
    }
#pragma unroll
    for (int nt = 0; nt < 4; nt++) {
      bh[nt] = *(const short8*)&Bh[wc + nt * 16 + lrow][koff];
      bl[nt] = *(const short8*)&Bl[wc + nt * 16 + lrow][koff];
    }
#pragma unroll
    for (int mt = 0; mt < 2; mt++)
#pragma unroll
      for (int nt = 0; nt < 4; nt++) {
        acc[mt][nt] = __builtin_amdgcn_mfma_f32_16x16x32_bf16(ah[mt], bh[nt], acc[mt][nt], 0, 0, 0);
        acc[mt][nt] = __builtin_amdgcn_mfma_f32_16x16x32_bf16(ah[mt], bl[nt], acc[mt][nt], 0, 0, 0);
        acc[mt][nt] = __builtin_amdgcn_mfma_f32_16x16x32_bf16(al[mt], bh[nt], acc[mt][nt], 0, 0, 0);
      }
    __syncthreads();
  }
  float* op = Pm + ((size_t)z * Mtot) * 4096 + j0;
#pragma unroll
  for (int mt = 0; mt < 2; mt++)
#pragma unroll
    for (int nt = 0; nt < 4; nt++) {
      int col = wc + nt * 16 + lrow;
#pragma unroll
      for (int r = 0; r < 4; r++) {
        int row = wr + mt * 16 + (lane >> 4) * 4 + r;
        op[(size_t)row * 4096 + col] = acc[mt][nt][r];
      }
    }
}

// reduce split-K partials + both biases, time-major remap:
// G[(m%10)*64 + m/10][j] = sum_z part[z][m][j] + b1[j] + b2[j]
__global__ __launch_bounds__(256) void reduce_in_k(const float* __restrict__ Pm,
                                                   const float* __restrict__ b1,
                                                   const float* __restrict__ b2,
                                                   float* __restrict__ G, int S)
{
  int idx = blockIdx.x * 256 + threadIdx.x;      // 0 .. 640*1024-1
  int m = idx >> 10, jq = idx & 1023;
  size_t col = (size_t)jq * 4;
  float4 s = *(const float4*)(Pm + (size_t)m * 4096 + col);
  for (int p = 1; p < S; p++) {
    float4 v = *(const float4*)(Pm + ((size_t)p * 640 + m) * 4096 + col);
    s.x += v.x; s.y += v.y; s.z += v.z; s.w += v.w;
  }
  float4 u1 = *(const float4*)(b1 + col);
  float4 u2 = *(const float4*)(b2 + col);
  int orow = (m % 10) * 64 + m / 10;
  float4 o = {s.x + u1.x + u2.x, s.y + u1.y + u2.y,
              s.z + u1.z + u2.z, s.w + u1.w + u2.w};
  *(float4*)(G + (size_t)orow * 4096 + col) = o;
}

// ---------------- LSTM cell ----------------
__global__ __launch_bounds__(256) void lstm_cell_k(const float* __restrict__ Gt,
                                                   const float* __restrict__ part,
                                                   float* __restrict__ h,
                                                   float* __restrict__ c,
                                                   float* __restrict__ yout, int t)
{
  const int idx = blockIdx.x * 256 + threadIdx.x;   // 0..65535
  const int b = idx >> 10, j = idx & 1023;
  const float* gb = Gt + (size_t)b * 4096;
  float gi = gb[j], gf = gb[1024 + j], gg = gb[2048 + j], go = gb[3072 + j];
#pragma unroll
  for (int p = 0; p < 8; p++) {
    const float* pp = part + (size_t)p * 262144 + (size_t)b * 4096;
    gi += pp[j]; gf += pp[1024 + j]; gg += pp[2048 + j]; go += pp[3072 + j];
  }
  float cp = c[idx];
  float si = 1.f / (1.f + expf(-gi));
  float sf = 1.f / (1.f + expf(-gf));
  float so = 1.f / (1.f + expf(-go));
  float tg = tanhf(gg);
  float cn = sf * cp + si * tg;
  float hn = so * tanhf(cn);
  c[idx] = cn; h[idx] = hn;
  if (yout) yout[((size_t)b * 10 + t) * 1024 + j] = hn;
}

// ---------------- classifier ----------------
__global__ __launch_bounds__(64) void cls_k(const float* __restrict__ h1,
                                            const float* __restrict__ w,
                                            const float* __restrict__ b,
                                            float* __restrict__ out)
{
  const int bi = blockIdx.x / 5, c = blockIdx.x % 5, lane = threadIdx.x;
  float s = 0.f;
  for (int j = lane; j < 1024; j += 64)
    s = fmaf(h1[(size_t)bi * 1024 + j], w[(size_t)c * 1024 + j], s);
  for (int off = 32; off; off >>= 1) s += __shfl_down(s, off);
  if (lane == 0) out[bi * 5 + c] = s + b[c];
}

// ---------------------------------------------------------------------------
// workspace layout (bytes) — identical to round 2/4 (proven fit).
// whh hi/lo conversion buffers overlay the pin region (dead during the
// recurrent loops: pin is consumed by reduce_in_k before each loop starts,
// and rewritten by the next layer's input GEMM after the loop ends).
// whh conv needs 2 x 8,388,608 = 16.8MB < pin's 41.9MB.
// ---------------------------------------------------------------------------
enum : size_t {
  OFF_ST1 = 0, OFF_ST2 = 1024, OFF_ST3 = 2048,
  OFF_SC1 = 4096, OFF_SC2 = 4608, OFF_SC3 = 5120,
  OFF_H0 = 8192,
  OFF_C0 = OFF_H0 + 262144,
  OFF_H1 = OFF_C0 + 262144,
  OFF_C1 = OFF_H1 + 262144,
  ZERO_BYTES = OFF_C1 + 262144,                  // memset [0, 1,056,768)
  OFF_F1 = ZERO_BYTES,                           // 10,485,760
  OFF_SEQ = OFF_F1 + 10485760,                   // 10,485,760
  OFF_Y0 = OFF_SEQ + 10485760,                   // 2,621,440
  OFF_G0 = OFF_Y0 + 2621440,                     // 10,485,760
  OFF_G1 = OFF_G0 + 10485760,                    // 10,485,760
  OFF_PART = OFF_G1 + 10485760,                  // 8,388,608 (recurrent partials, 8x64x4096)
  OFF_BIG = OFF_PART + 8388608,
  OFF_Y1 = OFF_BIG,                              // 47,226,880 (conv phase)
  OFF_P1 = OFF_G0,                               // overlay: dead before G0 written
  OFF_Y2 = OFF_BIG,                              // 22,282,240 (y1 dead)
  OFF_P2 = OFF_BIG + 22282240,                   // 11,059,200
  OFF_Y3 = OFF_BIG,                              // 20,971,520 (y2 dead, < OFF_P2)
  OFF_PARTIN = OFF_BIG,                          // 41,943,040 (LSTM phase; convs dead)
  OFF_WHH_H = OFF_BIG,                           // 8,388,608 (overlays dead pin)
  OFF_WHH_L = OFF_BIG + 8388608,                 // 8,388,608
};

extern "C" void kernel_launch(void* const* d_in, const int* in_sizes, int n_in,
                              void* d_out, int out_size, void* d_ws, size_t ws_size,
                              hipStream_t stream)
{
  const float* data = (const float*)d_in[0];
  const float* u    = (const float*)d_in[1];
  const float* c1w  = (const float*)d_in[2];
  const float* c1b  = (const float*)d_in[3];
  const float* bn1g = (const float*)d_in[4];
  const float* bn1b = (const float*)d_in[5];
  const float* c2w  = (const float*)d_in[6];
  const float* c2b  = (const float*)d_in[7];
  const float* bn2g = (const float*)d_in[8];
  const float* bn2b = (const float*)d_in[9];
  const float* c3w  = (const float*)d_in[10];
  const float* c3b  = (const float*)d_in[11];
  const float* bn3g = (const float*)d_in[12];
  const float* bn3b = (const float*)d_in[13];
  const float* qw   = (const float*)d_in[14];
  const float* qb   = (const float*)d_in[15];
  const float* kw   = (const float*)d_in[16];
  const float* kb   = (const float*)d_in[17];
  const float* vw   = (const float*)d_in[18];
  const float* vb   = (const float*)d_in[19];
  const float* g1w  = (const float*)d_in[20];
  const float* g1b  = (const float*)d_in[21];
  const float* g2w  = (const float*)d_in[22];
  const float* g2b  = (const float*)d_in[23];
  const float* wih0 = (const float*)d_in[24];
  const float* whh0 = (const float*)d_in[25];
  const float* bih0 = (const float*)d_in[26];
  const float* bhh0 = (const float*)d_in[27];
  const float* wih1 = (const float*)d_in[28];
  const float* whh1 = (const float*)d_in[29];
  const float* bih1 = (const float*)d_in[30];
  const float* bhh1 = (const float*)d_in[31];
  const float* clsw = (const float*)d_in[32];
  const float* clsb = (const float*)d_in[33];

  char* ws = (char*)d_ws;
  double* st1 = (double*)(ws + OFF_ST1);
  double* st2 = (double*)(ws + OFF_ST2);
  double* st3 = (double*)(ws + OFF_ST3);
  float* sc1 = (float*)(ws + OFF_SC1);
  float* sc2 = (float*)(ws + OFF_SC2);
  float* sc3 = (float*)(ws + OFF_SC3);
  float* h0 = (float*)(ws + OFF_H0);
  float* c0 = (float*)(ws + OFF_C0);
  float* h1 = (float*)(ws + OFF_H1);
  float* c1s = (float*)(ws + OFF_C1);
  float* f1b = (float*)(ws + OFF_F1);
  float* seq = (float*)(ws + OFF_SEQ);
  float* y0 = (float*)(ws + OFF_Y0);
  float* G0 = (float*)(ws + OFF_G0);
  float* G1 = (float*)(ws + OFF_G1);
  float* part = (float*)(ws + OFF_PART);
  float* y1 = (float*)(ws + OFF_Y1);
  float* p1 = (float*)(ws + OFF_P1);
  float* y2 = (float*)(ws + OFF_Y2);
  float* p2 = (float*)(ws + OFF_P2);
  float* y3 = (float*)(ws + OFF_Y3);
  float* pin = (float*)(ws + OFF_PARTIN);
  ushort* whhH = (ushort*)(ws + OFF_WHH_H);
  ushort* whhL = (ushort*)(ws + OFF_WHH_L);
  float* out = (float*)d_out;

  (void)in_sizes; (void)n_in; (void)out_size; (void)ws_size;

  // zero BN stat accumulators + LSTM states (ws is poisoned before each call)
  hipMemsetAsync(ws, 0, ZERO_BYTES, stream);

  // conv1 (+ fused NCH transpose of data), BN1, pool 8/4
  conv1d_k<8, 16, 32, 1184, 1153, 16, true><<<6400, 256, 0, stream>>>(data, c1w, c1b, y1);
  bn_stats_k<<<dim3(16, 10), 256, 0, stream>>>(y1, 16, 1153, st1);
  bn_fin_k<<<1, 64, 0, stream>>>(st1, bn1g, bn1b, 16, 1.0 / 737920.0, sc1);
  bn_pool_k<8, 4><<<11480, 256, 0, stream>>>(y1, sc1, 16, 1153, 287, 2938880, p1);

  // conv2, BN2, pool 4/2
  conv1d_k<16, 32, 16, 287, 272, 8, false><<<3200, 256, 0, stream>>>(p1, c2w, c2b, y2);
  bn_stats_k<<<dim3(32, 10), 256, 0, stream>>>(y2, 32, 272, st2);
  bn_fin_k<<<1, 64, 0, stream>>>(st2, bn2g, bn2b, 32, 1.0 / 174080.0, sc2);
  bn_pool_k<4, 2><<<10800, 256, 0, stream>>>(y2, sc2, 32, 272, 135, 2764800, p2);

  // conv3, BN3, pool 2/2 -> f1 (640,64,64)
  conv1d_k<32, 64, 8, 135, 128, 4, false><<<2560, 256, 0, stream>>>(p2, c3w, c3b, y3);
  bn_stats_k<<<dim3(64, 10), 256, 0, stream>>>(y3, 64, 128, st3);
  bn_fin_k<<<1, 64, 0, stream>>>(st3, bn3g, bn3b, 64, 1.0 / 81920.0, sc3);
  bn_pool_k<2, 2><<<10240, 256, 0, stream>>>(y3, sc3, 64, 128, 64, 2621440, f1b);

  // attention + gaussian adjacency + gumbel topk + deg + GCNx2 -> seq (640,4096)
  graph_fused_k<<<640, 256, 0, stream>>>(f1b, u, qw, qb, kw, kb, vw, vb,
                                         g1w, g1b, g2w, g2b, seq);

  // LSTM layer 0: split-K bf16-MFMA input projection (S=4) + reduce
  gemm_mfma_k<<<1280, 256, 0, stream>>>(seq, wih0, pin, 4096, 1024, 640, 10);
  reduce_in_k<<<2560, 256, 0, stream>>>(pin, bih0, bhh0, G0, 4);
  // pin dead -> pre-convert whh0 into its space (bit-identical staged values)
  conv_bf16_k<<<4096, 256, 0, stream>>>(whh0, whhH, whhL, 1048576);
  for (int t = 0; t < 10; t++) {
    gemm_rec_k<<<256, 256, 0, stream>>>(h0, whhH, whhL, part, 1024, 128, 64);
    lstm_cell_k<<<256, 256, 0, stream>>>(G0 + (size_t)t * 262144, part, h0, c0, y0, t);
  }

  // LSTM layer 1: input projection overwrites whh0 conv (loop 0 done)
  gemm_mfma_k<<<1280, 256, 0, stream>>>(y0, wih1, pin, 1024, 256, 640, 10);
  reduce_in_k<<<2560, 256, 0, stream>>>(pin, bih1, bhh1, G1, 4);
  conv_bf16_k<<<4096, 256, 0, stream>>>(whh1, whhH, whhL, 1048576);
  for (int t = 0; t < 10; t++) {
    gemm_rec_k<<<256, 256, 0, stream>>>(h1, whhH, whhL, part, 1024, 128, 64);
    lstm_cell_k<<<256, 256, 0, stream>>>(G1 + (size_t)t * 262144, part, h1, c1s, nullptr, t);
  }

  // classifier from final h1
  cls_k<<<320, 64, 0, stream>>>(h1, clsw, clsb, out);
}

// Round 10
// 1142.161 us; speedup vs baseline: 1.0708x; 1.0708x over previous
//
#include <hip/hip_runtime.h>
#include <cstdint>
#include <cstddef>

// ---------------------------------------------------------------------------
// MPML_57509612093615 : conv stack + BN + attention/GCN graph + 2-layer LSTM
// Round 14: bn_stats occupancy fix. Cross-round accounting (R2 coop run:
// everything-but-recurrent = 1010us) puts conv+BN+pool at ~570us, never yet
// profiled. bn_stats_k grids were (C,10) = 160/320/640 blocks = 0.6-2.5
// blocks/CU -> latency-bound serial row walks. Fix: slab 64 -> 8 rows,
// grids (C,80) = 1280/2560/5120 blocks (8x waves in flight). f64 sums +
// atomics unchanged (order change invisible at f64). Everything else
// byte-identical to R13 (1223us; R12/R13 within noise of best 1214).
// Shapes: B=64 T=10 SEG=1184 SIG=8 ADJ=64 HID=1024 NCLS=5, N=B*T=640
// ---------------------------------------------------------------------------

#define TOPK_K 1638

typedef short short8 __attribute__((ext_vector_type(8)));
typedef float fl4 __attribute__((ext_vector_type(4)));

// pad-every-8 LDS index: stride between 8-element groups becomes 9 banks
#define XI(l) ((l) + ((l) >> 3))

// ---------------- generic conv1d (rolling register window) ----------------
template<int CI, int CO, int K, int LIN, int LOUT, int NLG, bool XPOSED>
__global__ __launch_bounds__(256) void conv1d_k(const float* __restrict__ xin,
                                                const float* __restrict__ wg,
                                                const float* __restrict__ bg,
                                                float* __restrict__ y)
{
  constexpr int LT = 8;
  constexpr int CHUNK = NLG * LT;
  constexpr int NCHUNK = (LOUT + CHUNK - 1) / CHUNK;
  constexpr int TW = CHUNK + K - 1;
  constexpr int TWP = TW + (TW >> 3) + 2;
  __shared__ float xs[CI][TWP];
  __shared__ float ws[CI * K * CO];   // [ci][k][co]
  const int bx = blockIdx.x;
  const int n = bx / NCHUNK;
  const int l0 = (bx % NCHUNK) * CHUNK;
  const int tid = threadIdx.x;

  for (int i = tid; i < CI * K * CO; i += 256) {
    int co = i % CO, rest = i / CO;          // rest = ci*K + k
    ws[i] = wg[co * (CI * K) + rest];
  }
  if (XPOSED && CI == 8) {
    // conv1: one thread per position l, coalesced float4 x2 loads
    for (int dl = tid; dl < TW; dl += 256) {
      int l = l0 + dl;
      if (l < LIN) {
        const float* xp = xin + ((size_t)n * LIN + l) * 8;
        float4 v0 = *(const float4*)xp;
        float4 v1 = *(const float4*)(xp + 4);
        xs[0][XI(dl)] = v0.x; xs[1][XI(dl)] = v0.y;
        xs[2][XI(dl)] = v0.z; xs[3][XI(dl)] = v0.w;
        xs[4][XI(dl)] = v1.x; xs[5][XI(dl)] = v1.y;
        xs[6][XI(dl)] = v1.z; xs[7][XI(dl)] = v1.w;
      } else {
#pragma unroll
        for (int ci = 0; ci < 8; ci++) xs[ci][XI(dl)] = 0.f;
      }
    }
  } else {
    for (int i = tid; i < CI * TW; i += 256) {
      int ci = i / TW, dl = i % TW, l = l0 + dl;
      float v = 0.f;
      if (l < LIN) v = XPOSED ? xin[((size_t)n * LIN + l) * CI + ci]
                              : xin[((size_t)n * CI + ci) * LIN + l];
      xs[ci][XI(dl)] = v;
    }
  }
  __syncthreads();

  const int lg = tid % NLG, co = tid / NLG;  // NLG*CO == 256
  float acc[LT];
  const float bco = bg[co];
#pragma unroll
  for (int j = 0; j < LT; j++) acc[j] = bco;

  for (int ci = 0; ci < CI; ci++) {
    float win[LT];
#pragma unroll
    for (int j = 0; j < LT; j++) win[j] = xs[ci][XI(lg * LT + j)];
#pragma unroll
    for (int k = 0; k < K; k++) {
      const float wv = ws[(ci * K + k) * CO + co];
#pragma unroll
      for (int j = 0; j < LT; j++) acc[j] = fmaf(win[j], wv, acc[j]);
      if (k < K - 1) {
#pragma unroll
        for (int j = 0; j < LT - 1; j++) win[j] = win[j + 1];
        win[LT - 1] = xs[ci][XI(lg * LT + LT + k)];
      }
    }
  }
  float* yp = y + ((size_t)n * CO + co) * LOUT;
  const int lb = l0 + lg * LT;
#pragma unroll
  for (int j = 0; j < LT; j++)
    if (lb + j < LOUT) yp[lb + j] = acc[j];
}

// ---------------- BN stats (f64 accumulation, atomic) ----------------
// 8-row slabs: grid (C, 80) -> 1280/2560/5120 blocks (was (C,10): 160
// blocks = 0.6 blocks/CU, latency-bound). f64 precision order-invariant.
__global__ __launch_bounds__(256) void bn_stats_k(const float* __restrict__ y,
                                                  int C, int L,
                                                  double* __restrict__ st)
{
  const int c = blockIdx.x, slab = blockIdx.y, tid = threadIdx.x;
  double s = 0.0, q = 0.0;
  const int n0 = slab * 8;
  for (int n = n0; n < n0 + 8; n++) {
    const float* p = y + ((size_t)n * C + c) * L;
    for (int l = tid; l < L; l += 256) { float v = p[l]; s += v; q += (double)v * v; }
  }
  __shared__ double rs[256], rq[256];
  rs[tid] = s; rq[tid] = q; __syncthreads();
  for (int off = 128; off; off >>= 1) {
    if (tid < off) { rs[tid] += rs[tid + off]; rq[tid] += rq[tid + off]; }
    __syncthreads();
  }
  if (tid == 0) { atomicAdd(&st[c], rs[0]); atomicAdd(&st[C + c], rq[0]); }
}

__global__ void bn_fin_k(const double* __restrict__ st, const float* __restrict__ g,
                         const float* __restrict__ b, int C, double invcnt,
                         float* __restrict__ scsh)
{
  int c = threadIdx.x;
  if (c < C) {
    double m = st[c] * invcnt;
    double v = st[C + c] * invcnt - m * m;
    float sc = g[c] * (float)(1.0 / sqrt(v + 1e-5));
    scsh[c] = sc;
    scsh[C + c] = b[c] - (float)m * sc;
  }
}

// ---------------- BN apply + relu + maxpool ----------------
template<int WIN, int STRIDE>
__global__ __launch_bounds__(256) void bn_pool_k(const float* __restrict__ y,
                                                 const float* __restrict__ scsh,
                                                 int C, int LI, int LO, int total,
                                                 float* __restrict__ o)
{
  int idx = blockIdx.x * 256 + threadIdx.x;
  if (idx >= total) return;
  int j = idx % LO; int r = idx / LO; int c = r % C; int n = r / C;
  float sc = scsh[c], sh = scsh[C + c];
  const float* p = y + ((size_t)n * C + c) * LI + j * STRIDE;
  float m = 0.f;   // relu outputs are >= 0
#pragma unroll
  for (int k = 0; k < WIN; k++) {
    float v = fmaxf(fmaf(p[k], sc, sh), 0.f);
    m = fmaxf(m, v);
  }
  o[idx] = m;
}

// ---------------- graph-stage 64x64 matmuls, fl4 LDS both operands --------

// C = A @ B : acc[r][c] += sum_d Aa[i0+r][d] * Bb[d][j0+c]   (d-order exact)
__device__ __forceinline__ void mm_AB_l(float acc[4][4], const float (*Aa)[68],
                                        const float (*Bb)[68], int i0, int j0)
{
#pragma unroll
  for (int r = 0; r < 4; r++)
#pragma unroll
    for (int c = 0; c < 4; c++) acc[r][c] = 0.f;
#pragma unroll 4
  for (int d = 0; d < 64; d += 4) {
    fl4 a4[4];
#pragma unroll
    for (int r = 0; r < 4; r++) a4[r] = *(const fl4*)&Aa[i0 + r][d];
#pragma unroll
    for (int k = 0; k < 4; k++) {
      fl4 b4 = *(const fl4*)&Bb[d + k][j0];
#pragma unroll
      for (int r = 0; r < 4; r++)
#pragma unroll
        for (int c = 0; c < 4; c++) acc[r][c] = fmaf(a4[r][k], b4[c], acc[r][c]);
    }
  }
}

// C = A^T @ B : acc[r][c] += sum_d Aa[d][i0+r] * Bb[d][j0+c]
__device__ __forceinline__ void mm_AtB_l(float acc[4][4], const float (*Aa)[68],
                                         const float (*Bb)[68], int i0, int j0)
{
#pragma unroll
  for (int r = 0; r < 4; r++)
#pragma unroll
    for (int c = 0; c < 4; c++) acc[r][c] = 0.f;
#pragma unroll 4
  for (int d = 0; d < 64; d++) {
    fl4 a4 = *(const fl4*)&Aa[d][i0];
    fl4 b4 = *(const fl4*)&Bb[d][j0];
#pragma unroll
    for (int r = 0; r < 4; r++)
#pragma unroll
      for (int c = 0; c < 4; c++) acc[r][c] = fmaf(a4[r], b4[c], acc[r][c]);
  }
}

// direct stage: W[row][col] = src[row*64+col] (vectorized, conflict-clean)
__device__ __forceinline__ void stage_w_direct(float (*W)[68],
                                               const float* __restrict__ src, int tid)
{
  for (int fi = tid; fi < 1024; fi += 256) {
    int row = fi >> 4, cq = fi & 15;
    *(fl4*)&W[row][cq * 4] = *(const fl4*)&src[row * 64 + cq * 4];
  }
}

// transpose stage: W[d][j] = src[j*64+d] (coalesced reads, scalar writes)
__device__ __forceinline__ void stage_w_xpose(float (*W)[68],
                                              const float* __restrict__ src, int tid)
{
  for (int e = tid; e < 4096; e += 256)
    W[e & 63][e >> 6] = src[e];
}

// 256-thread row softmax: 4 threads per row (consecutive lanes), shfl_xor combine
__device__ __forceinline__ void softmax_rows256(float (*M)[68], int tid)
{
  const int row = tid >> 2, q = tid & 3, c0 = q * 16;
  float mx = -3.4e38f;
#pragma unroll
  for (int j = 0; j < 16; j++) mx = fmaxf(mx, M[row][c0 + j]);
  mx = fmaxf(mx, __shfl_xor(mx, 1));
  mx = fmaxf(mx, __shfl_xor(mx, 2));
  float s = 0.f;
#pragma unroll
  for (int j = 0; j < 16; j++) {
    float e = expf(M[row][c0 + j] - mx);
    M[row][c0 + j] = e; s += e;
  }
  s += __shfl_xor(s, 1);
  s += __shfl_xor(s, 2);
  float inv = 1.f / s;
#pragma unroll
  for (int j = 0; j < 16; j++) M[row][c0 + j] *= inv;
}

__device__ __forceinline__ unsigned f2key(float f)
{
  unsigned b = __float_as_uint(f);
  return (b & 0x80000000u) ? ~b : (b | 0x80000000u);
}

// one block per n: QKV attention + gaussian adj + gumbel topk + deg + GCNx2
__global__ __launch_bounds__(256) void graph_fused_k(
    const float* __restrict__ f1g, const float* __restrict__ u,
    const float* __restrict__ qw, const float* __restrict__ qb,
    const float* __restrict__ kw, const float* __restrict__ kb,
    const float* __restrict__ vw, const float* __restrict__ vb,
    const float* __restrict__ g1w, const float* __restrict__ g1b,
    const float* __restrict__ g2w, const float* __restrict__ g2b,
    float* __restrict__ seq)
{
  __shared__ __align__(16) float A[64][68], P[64][68], R[64][68], W[64][68];
  __shared__ float r2s[64], c2s[64], dv[64];
  __shared__ int cnt32[32];
  const int n = blockIdx.x, tid = threadIdx.x;
  const int tr = tid >> 4, tc = tid & 15, i0 = tr * 4, j0 = tc * 4;
  float acc[4][4];

  const float* fp = f1g + (size_t)n * 4096;
  stage_w_direct(A, fp, tid);                       // A = f1 (vectorized copy)
  stage_w_xpose(W, qw, tid);                        // W[d][j] = qw[j][d]
  __syncthreads();
  mm_AB_l(acc, A, W, i0, j0);                       // Q = f1 @ qw^T
#pragma unroll
  for (int r = 0; r < 4; r++)
#pragma unroll
    for (int c = 0; c < 4; c++) P[i0 + r][j0 + c] = acc[r][c] + qb[j0 + c];
  __syncthreads();
  stage_w_xpose(W, kw, tid);
  __syncthreads();
  mm_AB_l(acc, A, W, i0, j0);                       // K = f1 @ kw^T
#pragma unroll
  for (int r = 0; r < 4; r++)
#pragma unroll
    for (int c = 0; c < 4; c++) R[i0 + r][j0 + c] = acc[r][c] + kb[j0 + c];
  __syncthreads();
  mm_AtB_l(acc, R, P, i0, j0);                      // att_pre[w][v] = sum_h K[h][w]Q[h][v]
  __syncthreads();
#pragma unroll
  for (int r = 0; r < 4; r++)
#pragma unroll
    for (int c = 0; c < 4; c++) P[i0 + r][j0 + c] = 0.125f * acc[r][c];
  __syncthreads();
  softmax_rows256(P, tid);                          // P = att
  __syncthreads();
  stage_w_xpose(W, vw, tid);
  __syncthreads();
  mm_AB_l(acc, A, W, i0, j0);                       // V = f1 @ vw^T
#pragma unroll
  for (int r = 0; r < 4; r++)
#pragma unroll
    for (int c = 0; c < 4; c++) R[i0 + r][j0 + c] = acc[r][c] + vb[j0 + c];  // R = V
  __syncthreads();
  mm_AB_l(acc, R, P, i0, j0);                       // adj_att = V @ att
  __syncthreads();
#pragma unroll
  for (int r = 0; r < 4; r++)
#pragma unroll
    for (int c = 0; c < 4; c++) R[i0 + r][j0 + c] = acc[r][c];
  __syncthreads();
  softmax_rows256(R, tid);                          // R = S1
  __syncthreads();
  mm_AB_l(acc, A, A, i0, j0);                       // cross = f1 @ f1
  if (tid < 64) {
    float s = 0.f;
#pragma unroll
    for (int k = 0; k < 16; k++) {
      fl4 v = *(const fl4*)&A[tid][k * 4];
      s = fmaf(v[0], v[0], s); s = fmaf(v[1], v[1], s);
      s = fmaf(v[2], v[2], s); s = fmaf(v[3], v[3], s);
    }
    r2s[tid] = s;
  } else if (tid < 128) {
    int j = tid - 64; float s = 0.f;
    for (int d = 0; d < 64; d++) { float v = A[d][j]; s = fmaf(v, v, s); }
    c2s[j] = s;
  }
  __syncthreads();
#pragma unroll
  for (int r = 0; r < 4; r++)
#pragma unroll
    for (int c = 0; c < 4; c++) P[i0 + r][j0 + c] = acc[r][c];  // P = cross
  __syncthreads();
  for (int e = tid; e < 4096; e += 256) {
    int i = e >> 6, j = e & 63;
    P[i][j] = expf(-0.5f * (r2s[i] + c2s[j] - 2.f * P[i][j])); // adj_g, SIGMA=1
  }
  __syncthreads();
  softmax_rows256(P, tid);                          // P = S2
  __syncthreads();
  const float* un = u + (size_t)n * 4096;
  for (int e = tid; e < 4096; e += 256) {
    int i = e >> 6, j = e & 63;
    float uu = un[e];
    float gmb = -logf(-logf(uu + 1e-20f) + 1e-20f);
    R[i][j] = R[i][j] + P[i][j] + gmb;              // R = adj + gumbel
  }
  for (int i = tid; i < 32; i += 256) cnt32[i] = 0;
  __syncthreads();

  // exact radix select: TOPK_K-th largest of the 4096 values in R
  unsigned key[16];
#pragma unroll
  for (int e8 = 0; e8 < 16; e8++) {
    int e = tid * 16 + e8;
    key[e8] = f2key(R[e >> 6][e & 63]);
  }
  int kk = TOPK_K; unsigned high = 0u;
  for (int bit = 31; bit >= 0; bit--) {
    unsigned pref = (high >> bit) | 1u;
    int c_ = 0;
#pragma unroll
    for (int e8 = 0; e8 < 16; e8++) c_ += (int)((key[e8] >> bit) == pref);
    for (int off = 32; off; off >>= 1) c_ += __shfl_down(c_, off);
    if ((tid & 63) == 0) atomicAdd(&cnt32[bit], c_);
    __syncthreads();
    int tot = cnt32[bit];
    if (tot >= kk) high |= (1u << bit); else kk -= tot;
  }
  // deg over columns; diagonal forced to 1
  if (tid < 64) {
    int j = tid, dg = 1;
    for (int i = 0; i < 64; i++)
      if (i != j) dg += (int)(f2key(R[i][j]) >= high);
    dv[j] = 1.f / sqrtf((float)dg);
  }
  __syncthreads();
  for (int e = tid; e < 4096; e += 256) { int i = e >> 6; A[i][e & 63] *= dv[i]; }
  stage_w_direct(W, g1w, tid);                      // g1w already [d][j]
  __syncthreads();
  mm_AB_l(acc, A, W, i0, j0);                       // f2 pre-activation
  __syncthreads();
#pragma unroll
  for (int r = 0; r < 4; r++)
#pragma unroll
    for (int c = 0; c < 4; c++)
      P[i0 + r][j0 + c] = fmaxf(acc[r][c] + g1b[j0 + c], 0.f) * dv[i0 + r]; // dinv*f2
  stage_w_direct(W, g2w, tid);
  __syncthreads();
  mm_AB_l(acc, P, W, i0, j0);                       // f3 pre-activation
  float* sp = seq + (size_t)n * 4096;
#pragma unroll
  for (int r = 0; r < 4; r++)
#pragma unroll
    for (int c = 0; c < 4; c++)
      sp[(i0 + r) * 64 + j0 + c] = fmaxf(acc[r][c] + g2b[j0 + c], 0.f);
}

// ---------------- bf16 split helpers ----------------
__device__ __forceinline__ ushort f2bf_hi(float x)
{
  union { float f; unsigned u; } v; v.f = x;
  unsigned r = v.u + 0x7FFFu + ((v.u >> 16) & 1u);   // RNE to bf16
  return (ushort)(r >> 16);
}
__device__ __forceinline__ float bf2f(ushort h)
{
  union { unsigned u; float f; } v; v.u = ((unsigned)h) << 16;
  return v.f;
}

// ---------------- one-time fp32 -> bf16 hi/lo pre-conversion ----------------
// Same f2bf formulas as in-kernel staging -> bit-identical staged values.
__global__ __launch_bounds__(256) void conv_bf16_k(const float* __restrict__ src,
                                                   ushort* __restrict__ hi,
                                                   ushort* __restrict__ lo, int n4)
{
  int idx = blockIdx.x * 256 + threadIdx.x;
  if (idx >= n4) return;
  float4 v = *(const float4*)(src + (size_t)idx * 4);
  ushort h0 = f2bf_hi(v.x), h1 = f2bf_hi(v.y), h2 = f2bf_hi(v.z), h3 = f2bf_hi(v.w);
  uint2 hp = { (unsigned)h0 | ((unsigned)h1 << 16),
               (unsigned)h2 | ((unsigned)h3 << 16) };
  *(uint2*)(hi + (size_t)idx * 4) = hp;
  ushort l0 = f2bf_hi(v.x - bf2f(h0)), l1 = f2bf_hi(v.y - bf2f(h1));
  ushort l2 = f2bf_hi(v.z - bf2f(h2)), l3 = f2bf_hi(v.w - bf2f(h3));
  uint2 lp = { (unsigned)l0 | ((unsigned)l1 << 16),
               (unsigned)l2 | ((unsigned)l3 << 16) };
  *(uint2*)(lo + (size_t)idx * 4) = lp;
}

// ---------------- split-K GEMM via bf16-split MFMA (fp32 inputs) ----------
// part[z][m][j] = sum_{k in slice z} A[m][k]*B[j][k]   (3-product bf16 split)
// 1D grid nwg = MBLK*32*S, block 256 (4 waves, each 32x64 of 64x128 tile).
// XCD-chunked swizzle: swz=(flat&7)*(nwg/8)+flat/8 (bijective, nwg%8==0).
__global__ __launch_bounds__(256) void gemm_mfma_k(const float* __restrict__ Am,
                                                   const float* __restrict__ Bm,
                                                   float* __restrict__ Pm,
                                                   int KD, int KS, int Mtot, int MBLK)
{
  __shared__ __align__(16) ushort Ah[64][40], Al[64][40];
  __shared__ __align__(16) ushort Bh[128][40], Bl[128][40];
  const int nwg = gridDim.x;
  const int flat = blockIdx.x;
  const int swz = (flat & 7) * (nwg >> 3) + (flat >> 3);
  const int mb = swz % MBLK;
  const int rr = swz / MBLK;
  const int jb = rr & 31, z = rr >> 5;
  const int m0 = mb * 64, j0 = jb * 128;
  const int kbeg = z * KS;
  const int tid = threadIdx.x;
  const int wave = tid >> 6, lane = tid & 63;
  const int wr = (wave >> 1) * 32, wc = (wave & 1) * 64;
  const int lrow = lane & 15, koff = (lane >> 4) * 8;
  fl4 acc[2][4] = {};

  for (int kc = 0; kc < KS; kc += 32) {
    const int k0 = kbeg + kc;
    // stage A tile 64x32 (fp32 -> bf16 hi/lo)
#pragma unroll
    for (int i = 0; i < 2; i++) {
      int fi = tid + i * 256, m = fi >> 3, kq = fi & 7;
      float4 v = *(const float4*)(Am + (size_t)(m0 + m) * KD + k0 + kq * 4);
      ushort h0 = f2bf_hi(v.x), h1 = f2bf_hi(v.y), h2 = f2bf_hi(v.z), h3 = f2bf_hi(v.w);
      uint2 hp = { (unsigned)h0 | ((unsigned)h1 << 16),
                   (unsigned)h2 | ((unsigned)h3 << 16) };
      *(uint2*)&Ah[m][kq * 4] = hp;
      ushort l0 = f2bf_hi(v.x - bf2f(h0)), l1 = f2bf_hi(v.y - bf2f(h1));
      ushort l2 = f2bf_hi(v.z - bf2f(h2)), l3 = f2bf_hi(v.w - bf2f(h3));
      uint2 lp = { (unsigned)l0 | ((unsigned)l1 << 16),
                   (unsigned)l2 | ((unsigned)l3 << 16) };
      *(uint2*)&Al[m][kq * 4] = lp;
    }
    // stage B tile 128x32
#pragma unroll
    for (int i = 0; i < 4; i++) {
      int fi = tid + i * 256, j = fi >> 3, kq = fi & 7;
      float4 v = *(const float4*)(Bm + (size_t)(j0 + j) * KD + k0 + kq * 4);
      ushort h0 = f2bf_hi(v.x), h1 = f2bf_hi(v.y), h2 = f2bf_hi(v.z), h3 = f2bf_hi(v.w);
      uint2 hp = { (unsigned)h0 | ((unsigned)h1 << 16),
                   (unsigned)h2 | ((unsigned)h3 << 16) };
      *(uint2*)&Bh[j][kq * 4] = hp;
      ushort l0 = f2bf_hi(v.x - bf2f(h0)), l1 = f2bf_hi(v.y - bf2f(h1));
      ushort l2 = f2bf_hi(v.z - bf2f(h2)), l3 = f2bf_hi(v.w - bf2f(h3));
      uint2 lp = { (unsigned)l0 | ((unsigned)l1 << 16),
                   (unsigned)l2 | ((unsigned)l3 << 16) };
      *(uint2*)&Bl[j][kq * 4] = lp;
    }
    __syncthreads();
    short8 ah[2], al[2], bh[4], bl[4];
#pragma unroll
    for (int mt = 0; mt < 2; mt++) {
      ah[mt] = *(const short8*)&Ah[wr + mt * 16 + lrow][koff];
      al[mt] = *(const short8*)&Al[wr + mt * 16 + lrow][koff];
    }
#pragma unroll
    for (int nt = 0; nt < 4; nt++) {
      bh[nt] = *(const short8*)&Bh[wc + nt * 16 + lrow][koff];
      bl[nt] = *(const short8*)&Bl[wc + nt * 16 + lrow][koff];
    }
#pragma unroll
    for (int mt = 0; mt < 2; mt++)
#pragma unroll
      for (int nt = 0; nt < 4; nt++) {
        acc[mt][nt] = __builtin_amdgcn_mfma_f32_16x16x32_bf16(ah[mt], bh[nt], acc[mt][nt], 0, 0, 0);
        acc[mt][nt] = __builtin_amdgcn_mfma_f32_16x16x32_bf16(ah[mt], bl[nt], acc[mt][nt], 0, 0, 0);
        acc[mt][nt] = __builtin_amdgcn_mfma_f32_16x16x32_bf16(al[mt], bh[nt], acc[mt][nt], 0, 0, 0);
      }
    __syncthreads();
  }
  float* op = Pm + ((size_t)z * Mtot + m0) * 4096 + j0;
#pragma unroll
  for (int mt = 0; mt < 2; mt++)
#pragma unroll
    for (int nt = 0; nt < 4; nt++) {
      int col = wc + nt * 16 + lrow;
#pragma unroll
      for (int r = 0; r < 4; r++) {
        int row = wr + mt * 16 + (lane >> 4) * 4 + r;
        op[(size_t)row * 4096 + col] = acc[mt][nt][r];
      }
    }
}

// ---------------- recurrent GEMM: pre-converted bf16 B, fp32 A ----------
// Same tile/fragment schedule as gemm_mfma_k; B staged by plain short8 copies
// from packed hi/lo buffers (no conversion VALU, half the staged ops).
// grid 256 = 32 jb x 8 z, MBLK=1 (m0=0), KS=128, KD=1024, Mtot=64.
__global__ __launch_bounds__(256) void gemm_rec_k(const float* __restrict__ Am,
                                                  const ushort* __restrict__ Bhg,
                                                  const ushort* __restrict__ Blg,
                                                  float* __restrict__ Pm,
                                                  int KD, int KS, int Mtot)
{
  __shared__ __align__(16) ushort Ah[64][40], Al[64][40];
  __shared__ __align__(16) ushort Bh[128][40], Bl[128][40];
  const int nwg = gridDim.x;
  const int flat = blockIdx.x;
  const int swz = (flat & 7) * (nwg >> 3) + (flat >> 3);
  const int jb = swz & 31, z = swz >> 5;
  const int j0 = jb * 128;
  const int kbeg = z * KS;
  const int tid = threadIdx.x;
  const int wave = tid >> 6, lane = tid & 63;
  const int wr = (wave >> 1) * 32, wc = (wave & 1) * 64;
  const int lrow = lane & 15, koff = (lane >> 4) * 8;
  fl4 acc[2][4] = {};

  for (int kc = 0; kc < KS; kc += 32) {
    const int k0 = kbeg + kc;
    // stage A tile 64x32 (fp32 -> bf16 hi/lo)
#pragma unroll
    for (int i = 0; i < 2; i++) {
      int fi = tid + i * 256, m = fi >> 3, kq = fi & 7;
      float4 v = *(const float4*)(Am + (size_t)m * KD + k0 + kq * 4);
      ushort h0 = f2bf_hi(v.x), h1 = f2bf_hi(v.y), h2 = f2bf_hi(v.z), h3 = f2bf_hi(v.w);
      uint2 hp = { (unsigned)h0 | ((unsigned)h1 << 16),
                   (unsigned)h2 | ((unsigned)h3 << 16) };
      *(uint2*)&Ah[m][kq * 4] = hp;
      ushort l0 = f2bf_hi(v.x - bf2f(h0)), l1 = f2bf_hi(v.y - bf2f(h1));
      ushort l2 = f2bf_hi(v.z - bf2f(h2)), l3 = f2bf_hi(v.w - bf2f(h3));
      uint2 lp = { (unsigned)l0 | ((unsigned)l1 << 16),
                   (unsigned)l2 | ((unsigned)l3 << 16) };
      *(uint2*)&Al[m][kq * 4] = lp;
    }
    // stage B tile 128x32: direct short8 copies from pre-converted buffers
#pragma unroll
    for (int i = 0; i < 2; i++) {
      int fi = tid + i * 256, j = fi >> 2, g8 = fi & 3;
      const size_t gsrc = (size_t)(j0 + j) * KD + k0 + g8 * 8;
      *(short8*)&Bh[j][g8 * 8] = *(const short8*)(Bhg + gsrc);
      *(short8*)&Bl[j][g8 * 8] = *(const short8*)(Blg + gsrc);
    }
    __syncthreads();
    short8 ah[2], al[2], bh[4], bl[4];
#pragma unroll
    for (int mt = 0; mt < 2; mt++) {
      ah[mt] = *(const short8*)&Ah[wr + mt * 16 + lrow][koff];
      al[mt] = *(const short8*)&Al[wr + mt * 16 + lrow][koff];
    }
#pragma unroll
    for (int nt = 0; nt < 4; nt++) {
      bh[nt] = *(const short8*)&Bh[wc + nt * 16 + lrow][koff];
      bl[nt] = *(const short8*)&Bl[wc + nt * 16 + lrow][koff];
    }
#pragma unroll
    for (int mt = 0; mt < 2; mt++)
#pragma unroll
      for (int nt = 0; nt < 4; nt++) {
        acc[mt][nt] = __builtin_amdgcn_mfma_f32_16x16x32_bf16(ah[mt], bh[nt], acc[mt][nt], 0, 0, 0);
        acc[mt][nt] = __builtin_amdgcn_mfma_f32_16x16x32_bf16(ah[mt], bl[nt], acc[mt][nt], 0, 0, 0);
        acc[mt][nt] = __builtin_amdgcn_mfma_f32_16x16x32_bf16(al[mt], bh[nt], acc[mt][nt], 0, 0, 0);
      }
    __syncthreads();
  }
  float* op = Pm + ((size_t)z * Mtot) * 4096 + j0;
#pragma unroll
  for (int mt = 0; mt < 2; mt++)
#pragma unroll
    for (int nt = 0; nt < 4; nt++) {
      int col = wc + nt * 16 + lrow;
#pragma unroll
      for (int r = 0; r < 4; r++) {
        int row = wr + mt * 16 + (lane >> 4) * 4 + r;
        op[(size_t)row * 4096 + col] = acc[mt][nt][r];
      }
    }
}

// reduce split-K partials + both biases, time-major remap:
// G[(m%10)*64 + m/10][j] = sum_z part[z][m][j] + b1[j] + b2[j]
__global__ __launch_bounds__(256) void reduce_in_k(const float* __restrict__ Pm,
                                                   const float* __restrict__ b1,
                                                   const float* __restrict__ b2,
                                                   float* __restrict__ G, int S)
{
  int idx = blockIdx.x * 256 + threadIdx.x;      // 0 .. 640*1024-1
  int m = idx >> 10, jq = idx & 1023;
  size_t col = (size_t)jq * 4;
  float4 s = *(const float4*)(Pm + (size_t)m * 4096 + col);
  for (int p = 1; p < S; p++) {
    float4 v = *(const float4*)(Pm + ((size_t)p * 640 + m) * 4096 + col);
    s.x += v.x; s.y += v.y; s.z += v.z; s.w += v.w;
  }
  float4 u1 = *(const float4*)(b1 + col);
  float4 u2 = *(const float4*)(b2 + col);
  int orow = (m % 10) * 64 + m / 10;
  float4 o = {s.x + u1.x + u2.x, s.y + u1.y + u2.y,
              s.z + u1.z + u2.z, s.w + u1.w + u2.w};
  *(float4*)(G + (size_t)orow * 4096 + col) = o;
}

// ---------------- LSTM cell ----------------
__global__ __launch_bounds__(256) void lstm_cell_k(const float* __restrict__ Gt,
                                                   const float* __restrict__ part,
                                                   float* __restrict__ h,
                                                   float* __restrict__ c,
                                                   float* __restrict__ yout, int t)
{
  const int idx = blockIdx.x * 256 + threadIdx.x;   // 0..65535
  const int b = idx >> 10, j = idx & 1023;
  const float* gb = Gt + (size_t)b * 4096;
  float gi = gb[j], gf = gb[1024 + j], gg = gb[2048 + j], go = gb[3072 + j];
#pragma unroll
  for (int p = 0; p < 8; p++) {
    const float* pp = part + (size_t)p * 262144 + (size_t)b * 4096;
    gi += pp[j]; gf += pp[1024 + j]; gg += pp[2048 + j]; go += pp[3072 + j];
  }
  float cp = c[idx];
  float si = 1.f / (1.f + expf(-gi));
  float sf = 1.f / (1.f + expf(-gf));
  float so = 1.f / (1.f + expf(-go));
  float tg = tanhf(gg);
  float cn = sf * cp + si * tg;
  float hn = so * tanhf(cn);
  c[idx] = cn; h[idx] = hn;
  if (yout) yout[((size_t)b * 10 + t) * 1024 + j] = hn;
}

// ---------------- classifier ----------------
__global__ __launch_bounds__(64) void cls_k(const float* __restrict__ h1,
                                            const float* __restrict__ w,
                                            const float* __restrict__ b,
                                            float* __restrict__ out)
{
  const int bi = blockIdx.x / 5, c = blockIdx.x % 5, lane = threadIdx.x;
  float s = 0.f;
  for (int j = lane; j < 1024; j += 64)
    s = fmaf(h1[(size_t)bi * 1024 + j], w[(size_t)c * 1024 + j], s);
  for (int off = 32; off; off >>= 1) s += __shfl_down(s, off);
  if (lane == 0) out[bi * 5 + c] = s + b[c];
}

// ---------------------------------------------------------------------------
// workspace layout (bytes) — identical to round 2/4 (proven fit).
// whh hi/lo conversion buffers overlay the pin region (dead during the
// recurrent loops).
// ---------------------------------------------------------------------------
enum : size_t {
  OFF_ST1 = 0, OFF_ST2 = 1024, OFF_ST3 = 2048,
  OFF_SC1 = 4096, OFF_SC2 = 4608, OFF_SC3 = 5120,
  OFF_H0 = 8192,
  OFF_C0 = OFF_H0 + 262144,
  OFF_H1 = OFF_C0 + 262144,
  OFF_C1 = OFF_H1 + 262144,
  ZERO_BYTES = OFF_C1 + 262144,                  // memset [0, 1,056,768)
  OFF_F1 = ZERO_BYTES,                           // 10,485,760
  OFF_SEQ = OFF_F1 + 10485760,                   // 10,485,760
  OFF_Y0 = OFF_SEQ + 10485760,                   // 2,621,440
  OFF_G0 = OFF_Y0 + 2621440,                     // 10,485,760
  OFF_G1 = OFF_G0 + 10485760,                    // 10,485,760
  OFF_PART = OFF_G1 + 10485760,                  // 8,388,608 (recurrent partials, 8x64x4096)
  OFF_BIG = OFF_PART + 8388608,
  OFF_Y1 = OFF_BIG,                              // 47,226,880 (conv phase)
  OFF_P1 = OFF_G0,                               // overlay: dead before G0 written
  OFF_Y2 = OFF_BIG,                              // 22,282,240 (y1 dead)
  OFF_P2 = OFF_BIG + 22282240,                   // 11,059,200
  OFF_Y3 = OFF_BIG,                              // 20,971,520 (y2 dead, < OFF_P2)
  OFF_PARTIN = OFF_BIG,                          // 41,943,040 (LSTM phase; convs dead)
  OFF_WHH_H = OFF_BIG,                           // 8,388,608 (overlays dead pin)
  OFF_WHH_L = OFF_BIG + 8388608,                 // 8,388,608
};

extern "C" void kernel_launch(void* const* d_in, const int* in_sizes, int n_in,
                              void* d_out, int out_size, void* d_ws, size_t ws_size,
                              hipStream_t stream)
{
  const float* data = (const float*)d_in[0];
  const float* u    = (const float*)d_in[1];
  const float* c1w  = (const float*)d_in[2];
  const float* c1b  = (const float*)d_in[3];
  const float* bn1g = (const float*)d_in[4];
  const float* bn1b = (const float*)d_in[5];
  const float* c2w  = (const float*)d_in[6];
  const float* c2b  = (const float*)d_in[7];
  const float* bn2g = (const float*)d_in[8];
  const float* bn2b = (const float*)d_in[9];
  const float* c3w  = (const float*)d_in[10];
  const float* c3b  = (const float*)d_in[11];
  const float* bn3g = (const float*)d_in[12];
  const float* bn3b = (const float*)d_in[13];
  const float* qw   = (const float*)d_in[14];
  const float* qb   = (const float*)d_in[15];
  const float* kw   = (const float*)d_in[16];
  const float* kb   = (const float*)d_in[17];
  const float* vw   = (const float*)d_in[18];
  const float* vb   = (const float*)d_in[19];
  const float* g1w  = (const float*)d_in[20];
  const float* g1b  = (const float*)d_in[21];
  const float* g2w  = (const float*)d_in[22];
  const float* g2b  = (const float*)d_in[23];
  const float* wih0 = (const float*)d_in[24];
  const float* whh0 = (const float*)d_in[25];
  const float* bih0 = (const float*)d_in[26];
  const float* bhh0 = (const float*)d_in[27];
  const float* wih1 = (const float*)d_in[28];
  const float* whh1 = (const float*)d_in[29];
  const float* bih1 = (const float*)d_in[30];
  const float* bhh1 = (const float*)d_in[31];
  const float* clsw = (const float*)d_in[32];
  const float* clsb = (const float*)d_in[33];

  char* ws = (char*)d_ws;
  double* st1 = (double*)(ws + OFF_ST1);
  double* st2 = (double*)(ws + OFF_ST2);
  double* st3 = (double*)(ws + OFF_ST3);
  float* sc1 = (float*)(ws + OFF_SC1);
  float* sc2 = (float*)(ws + OFF_SC2);
  float* sc3 = (float*)(ws + OFF_SC3);
  float* h0 = (float*)(ws + OFF_H0);
  float* c0 = (float*)(ws + OFF_C0);
  float* h1 = (float*)(ws + OFF_H1);
  float* c1s = (float*)(ws + OFF_C1);
  float* f1b = (float*)(ws + OFF_F1);
  float* seq = (float*)(ws + OFF_SEQ);
  float* y0 = (float*)(ws + OFF_Y0);
  float* G0 = (float*)(ws + OFF_G0);
  float* G1 = (float*)(ws + OFF_G1);
  float* part = (float*)(ws + OFF_PART);
  float* y1 = (float*)(ws + OFF_Y1);
  float* p1 = (float*)(ws + OFF_P1);
  float* y2 = (float*)(ws + OFF_Y2);
  float* p2 = (float*)(ws + OFF_P2);
  float* y3 = (float*)(ws + OFF_Y3);
  float* pin = (float*)(ws + OFF_PARTIN);
  ushort* whhH = (ushort*)(ws + OFF_WHH_H);
  ushort* whhL = (ushort*)(ws + OFF_WHH_L);
  float* out = (float*)d_out;

  (void)in_sizes; (void)n_in; (void)out_size; (void)ws_size;

  // zero BN stat accumulators + LSTM states (ws is poisoned before each call)
  hipMemsetAsync(ws, 0, ZERO_BYTES, stream);

  // conv1 (+ fused NCH transpose of data), BN1 (8-row slabs), pool 8/4
  conv1d_k<8, 16, 32, 1184, 1153, 16, true><<<6400, 256, 0, stream>>>(data, c1w, c1b, y1);
  bn_stats_k<<<dim3(16, 80), 256, 0, stream>>>(y1, 16, 1153, st1);
  bn_fin_k<<<1, 64, 0, stream>>>(st1, bn1g, bn1b, 16, 1.0 / 737920.0, sc1);
  bn_pool_k<8, 4><<<11480, 256, 0, stream>>>(y1, sc1, 16, 1153, 287, 2938880, p1);

  // conv2, BN2, pool 4/2
  conv1d_k<16, 32, 16, 287, 272, 8, false><<<3200, 256, 0, stream>>>(p1, c2w, c2b, y2);
  bn_stats_k<<<dim3(32, 80), 256, 0, stream>>>(y2, 32, 272, st2);
  bn_fin_k<<<1, 64, 0, stream>>>(st2, bn2g, bn2b, 32, 1.0 / 174080.0, sc2);
  bn_pool_k<4, 2><<<10800, 256, 0, stream>>>(y2, sc2, 32, 272, 135, 2764800, p2);

  // conv3, BN3, pool 2/2 -> f1 (640,64,64)
  conv1d_k<32, 64, 8, 135, 128, 4, false><<<2560, 256, 0, stream>>>(p2, c3w, c3b, y3);
  bn_stats_k<<<dim3(64, 80), 256, 0, stream>>>(y3, 64, 128, st3);
  bn_fin_k<<<1, 64, 0, stream>>>(st3, bn3g, bn3b, 64, 1.0 / 81920.0, sc3);
  bn_pool_k<2, 2><<<10240, 256, 0, stream>>>(y3, sc3, 64, 128, 64, 2621440, f1b);

  // attention + gaussian adjacency + gumbel topk + deg + GCNx2 -> seq (640,4096)
  graph_fused_k<<<640, 256, 0, stream>>>(f1b, u, qw, qb, kw, kb, vw, vb,
                                         g1w, g1b, g2w, g2b, seq);

  // LSTM layer 0: split-K bf16-MFMA input projection (S=4) + reduce
  gemm_mfma_k<<<1280, 256, 0, stream>>>(seq, wih0, pin, 4096, 1024, 640, 10);
  reduce_in_k<<<2560, 256, 0, stream>>>(pin, bih0, bhh0, G0, 4);
  // pin dead -> pre-convert whh0 into its space (bit-identical staged values)
  conv_bf16_k<<<4096, 256, 0, stream>>>(whh0, whhH, whhL, 1048576);
  for (int t = 0; t < 10; t++) {
    gemm_rec_k<<<256, 256, 0, stream>>>(h0, whhH, whhL, part, 1024, 128, 64);
    lstm_cell_k<<<256, 256, 0, stream>>>(G0 + (size_t)t * 262144, part, h0, c0, y0, t);
  }

  // LSTM layer 1: input projection overwrites whh0 conv (loop 0 done)
  gemm_mfma_k<<<1280, 256, 0, stream>>>(y0, wih1, pin, 1024, 256, 640, 10);
  reduce_in_k<<<2560, 256, 0, stream>>>(pin, bih1, bhh1, G1, 4);
  conv_bf16_k<<<4096, 256, 0, stream>>>(whh1, whhH, whhL, 1048576);
  for (int t = 0; t < 10; t++) {
    gemm_rec_k<<<256, 256, 0, stream>>>(h1, whhH, whhL, part, 1024, 128, 64);
    lstm_cell_k<<<256, 256, 0, stream>>>(G1 + (size_t)t * 262144, part, h1, c1s, nullptr, t);
  }

  // classifier from final h1
  cls_k<<<320, 64, 0, stream>>>(h1, clsw, clsb, out);
}